// Round 6
// baseline (27.498 us; speedup 1.0000x reference)
//
#include <hip/hip_runtime.h>
#include <math.h>

constexpr int Hn = 18, Wn = 18, HWn = 324;

// Four tiles per wave; 16-lane group g owns tile wave*4+g (row layout).
// Slots 0-19: element p = 4l + 64q + r (5 float4 loads); slot 20: tail
// p = 320+(l&3), valid only l<4.  Geometry computed once per slot
// (y = (p*57)>>10 exact for p<324, mul24-eligible after range-pinning
// py/px), d^2-1 stored u16-packed (11 VGPRs).  Peak pixel has d2-1 = -1
// -> 0xFFFF after masking: auto-excluded from the pass-B unsigned min,
// "survivor" in pass C, fixed by a closed-form correction.
__global__ __launch_bounds__(256, 8) void psrw_kernel(
    const float* __restrict__ cv, const int* __restrict__ peak,
    float* __restrict__ out, int BC)
{
    int gtid = blockIdx.x * 256 + threadIdx.x;
    int wave = gtid >> 6;
    int lane = threadIdx.x & 63;
    int g = lane >> 4;
    int l = lane & 15;
    int tile = wave * 4 + g;
    if (tile >= BC) return;

    const float* row = cv + (size_t)tile * HWn;
    int2 pk = ((const int2*)peak)[tile];
    int py = pk.x & 31, px = pk.y & 31;   // range-pin: enables mul24

    const float4* rf4 = (const float4*)row;
    float4 v0 = rf4[l];
    float4 v1 = rf4[l + 16];
    float4 v2 = rf4[l + 32];
    float4 v3 = rf4[l + 48];
    float4 v4 = rf4[l + 64];
    bool vt = (l < 4);
    float c20 = row[320 + (l & 3)];       // same line for all lanes; L1
    if (!vt) c20 = 0.f;

    float c[21] = {v0.x, v0.y, v0.z, v0.w, v1.x, v1.y, v1.z, v1.w,
                   v2.x, v2.y, v2.z, v2.w, v3.x, v3.y, v3.z, v3.w,
                   v4.x, v4.y, v4.z, v4.w, c20};

    float cpk = row[py * Wn + px];        // peak value (uniform per group)

    // ---- Pass A: max + total sum; rect sum gathered by lanes 0..8 ----
    float m0 = -INFINITY, m1 = -INFINITY, s0 = 0.f, s1 = 0.f;
#pragma unroll
    for (int j = 0; j < 20; j += 2) { m0 = fmaxf(m0, c[j]); s0 += c[j]; }
#pragma unroll
    for (int j = 1; j < 20; j += 2) { m1 = fmaxf(m1, c[j]); s1 += c[j]; }
    s0 += c[20];
    m0 = fmaxf(m0, vt ? c[20] : -INFINITY);
    float m = fmaxf(m0, m1);
    float s = s0 + s1;

    int ry0 = max(0, py - 1), ry1 = min(Hn - 1, py + 1);
    int rx0 = max(0, px - 1), rx1 = min(Wn - 1, px + 1);
    float rectc = 0.f;
    if (l < 9) {
        int q = (l * 11) >> 5;            // l/3 for l<=8
        int r = l - 3 * q;
        int ry = ry0 + q, rx = rx0 + r;
        if (ry <= ry1 && rx <= rx1) rectc = row[ry * Wn + rx];  // L1 hit
    }
    s -= rectc;                           // fold rect removal into reduction
#pragma unroll
    for (int o = 8; o; o >>= 1) {
        s += __shfl_xor(s, o, 64);
        m = fmaxf(m, __shfl_xor(m, o, 64));
    }
    int n_pri = HWn - (ry1 - ry0 + 1) * (rx1 - rx0 + 1);
    float mean_pri = s / (float)n_pri;    // IEEE: feeds the keep-compare cliff

    // ---- Pass B: dminb = min over {c<=mean_pri} of (d2-1); pack d2-1 u16 ----
    int l4 = 4 * l;
    unsigned dminb = 0xFFFFFFFFu;
    unsigned packed[11];
#pragma unroll
    for (int jj = 0; jj <= 10; ++jj) {
        int j0 = 2 * jj;
        // slot j0
        int p0 = (j0 < 20) ? (l4 + 64 * (j0 >> 2) + (j0 & 3)) : (320 + (l & 3));
        int y0 = (p0 * 57) >> 10;
        int x0 = p0 - 18 * y0;
        int dy0 = y0 - py, dx0 = x0 - px;
        unsigned a = (unsigned)(dy0 * dy0 + dx0 * dx0 - 1) & 0xFFFFu;
        if (j0 == 20 && !vt) a = 0x7FFFu; // invalid tail slot: far, not in-disk
        unsigned t = min(dminb, a);
        dminb = (c[j0] <= mean_pri) ? t : dminb;
        unsigned pr = a;
        if (j0 + 1 < 21) {                // slot j0+1 (always <20 here)
            int p1 = l4 + 64 * ((j0 + 1) >> 2) + ((j0 + 1) & 3);
            int y1 = (p1 * 57) >> 10;
            int x1 = p1 - 18 * y1;
            int dy1 = y1 - py, dx1 = x1 - px;
            unsigned b2 = (unsigned)(dy1 * dy1 + dx1 * dx1 - 1) & 0xFFFFu;
            t = min(dminb, b2);
            dminb = (c[j0 + 1] <= mean_pri) ? t : dminb;
            pr |= (b2 << 16);
        }
        packed[jj] = pr;
    }
#pragma unroll
    for (int o = 8; o; o >>= 1)
        dminb = min(dminb, (unsigned)__shfl_xor((int)dminb, o, 64));

    // width = sqrt(dmin) (sentinel 100); disk test d2 <= clip(dmin,2,20) exact
    float width = (dminb > 577u) ? 100.f
                                 : __builtin_amdgcn_sqrtf((float)(dminb + 1u));
    unsigned rad2m1 = min(max(dminb, 1u), 19u);

    // ---- Pass C: survivors (d2-1 > rad2m1): sum, sumsq, in-disk count ----
    float sd0 = 0.f, sd1 = 0.f, ssd = 0.f;
    int cnt = 0;
#pragma unroll
    for (int jj = 0; jj <= 10; ++jj) {
        unsigned pr = packed[jj];
        unsigned a = pr & 0xFFFFu;
        bool in = (a <= rad2m1);          // peak: 0xFFFF -> "survivor" (fixed below)
        float cm = in ? 0.f : c[2 * jj];
        sd0 += cm;
        ssd = fmaf(cm, cm, ssd);
        cnt += in ? 1 : 0;
        if (2 * jj + 1 < 21) {
            unsigned b2 = pr >> 16;
            bool in2 = (b2 <= rad2m1);
            float cm2 = in2 ? 0.f : c[2 * jj + 1];
            sd1 += cm2;
            ssd = fmaf(cm2, cm2, ssd);
            cnt += in2 ? 1 : 0;
        }
    }
    float sd = sd0 + sd1;
#pragma unroll
    for (int o = 8; o; o >>= 1) {
        sd  += __shfl_xor(sd, o, 64);
        ssd += __shfl_xor(ssd, o, 64);
        cnt += __shfl_xor(cnt, o, 64);
    }
    // peak correction: it is always in-disk (d2=0 <= rad2 since rad2>=2)
    sd -= cpk;
    ssd = fmaf(-cpk, cpk, ssd);
    float n = (float)(HWn - 1 - cnt);
    float mean_s = sd * __builtin_amdgcn_rcpf(n);
    float var_s = fmaf(-sd, mean_s, ssd) * __builtin_amdgcn_rcpf(n - 1.f);
    float psrw = (m - mean_s) * __builtin_amdgcn_rcpf(fmaf(var_s, width, 1e-16f));
    if (l == 0) out[tile] = psrw;
}

// Normalize each b-row of C=324 psrw values by (mean + 1e-8), in place.
__global__ __launch_bounds__(256) void norm_kernel(float* __restrict__ out, int B)
{
    int gtid = blockIdx.x * 256 + threadIdx.x;
    int wave = gtid >> 6;
    int lane = threadIdx.x & 63;
    if (wave >= B) return;
    float* row = out + (size_t)wave * HWn;
    float4 v0 = reinterpret_cast<float4*>(row)[lane];
    bool has2 = lane < 17;
    float4 v1 = make_float4(0.f, 0.f, 0.f, 0.f);
    if (has2) v1 = reinterpret_cast<float4*>(row)[64 + lane];
    float s = (v0.x + v0.y) + (v0.z + v0.w) + ((v1.x + v1.y) + (v1.z + v1.w));
#pragma unroll
    for (int o = 32; o; o >>= 1) s += __shfl_xor(s, o, 64);
    float denom = s / 324.0f + 1e-8f;
    v0.x /= denom; v0.y /= denom; v0.z /= denom; v0.w /= denom;
    reinterpret_cast<float4*>(row)[lane] = v0;
    if (has2) {
        v1.x /= denom; v1.y /= denom; v1.z /= denom; v1.w /= denom;
        reinterpret_cast<float4*>(row)[64 + lane] = v1;
    }
}

extern "C" void kernel_launch(void* const* d_in, const int* in_sizes, int n_in,
                              void* d_out, int out_size, void* d_ws, size_t ws_size,
                              hipStream_t stream) {
    const float* cv  = (const float*)d_in[0];
    const int* peak  = (const int*)d_in[1];
    // d_in[2]/d_in[3] (mesh_y/mesh_x) are broadcast index grids — recomputed.
    float* out = (float*)d_out;

    int BC = in_sizes[1] / 2;               // 82944 tiles
    int waves = (BC + 3) / 4;               // 4 tiles per wave
    int blocks1 = (waves + 3) / 4;          // 4 waves per 256-thread block
    psrw_kernel<<<blocks1, 256, 0, stream>>>(cv, peak, out, BC);

    int B = out_size / HWn;
    int blocks2 = (B + 3) / 4;
    norm_kernel<<<blocks2, 256, 0, stream>>>(out, B);
}

// Round 7
// 27.093 us; speedup vs baseline: 1.0149x; 1.0149x over previous
//
#include <hip/hip_runtime.h>
#include <math.h>

constexpr int Hn = 18, Wn = 18, HWn = 324;
constexpr int CHn = 324;   // channels per batch row (== HWn coincidentally)

// Load one tile's 324 floats into a 16-lane group's 21 register slots
// (column layout: lane l owns column x=l, slots j=0..17 = element j*18+l;
// tails: slot 18+s -> (y=8s+(l>>1), x=16+(l&1)), slot 20 valid only l<4).
__device__ __forceinline__ void load_tile(const float* __restrict__ cvb,
                                          const int* __restrict__ pkb,
                                          int t, int l,
                                          float (&c)[21], int2 &pk)
{
    pk = ((const int2*)pkb)[t];
    const float* row = cvb + (size_t)t * HWn;
    const float* colp = row + l;
#pragma unroll
    for (int j = 0; j < 18; ++j) c[j] = colp[18 * j];   // imm-offset loads
    const float* tp = row + ((l >> 1) * 18 + 16 + (l & 1));
    c[18] = tp[0];
    c[19] = tp[144];
    c[20] = (l < 4) ? tp[288] : 0.f;
}

// Per-tile PSRW: arithmetic identical to the round-4 passing kernel.
__device__ __forceinline__ float compute_psrw(const float (&c)[21], int2 pkc,
                                              int l, const float* __restrict__ row)
{
    int py = pkc.x & 31, px = pkc.y & 31;   // range-pin: enables mul24
    float cpk = row[py * Wn + px];          // L1-hot (tile just loaded)
    bool v20 = (l < 4);

    // ---- Pass A: max + total sum; rect gathered by lanes 0..8 ----
    float m0 = -INFINITY, m1 = -INFINITY, s0 = 0.f, s1 = 0.f;
#pragma unroll
    for (int j = 0; j < 18; j += 2) { m0 = fmaxf(m0, c[j]); s0 += c[j]; }
#pragma unroll
    for (int j = 1; j < 18; j += 2) { m1 = fmaxf(m1, c[j]); s1 += c[j]; }
    m0 = fmaxf(m0, c[18]); s0 += c[18];
    m1 = fmaxf(m1, c[19]); s1 += c[19];
    m0 = fmaxf(m0, v20 ? c[20] : -INFINITY); s0 += c[20];
    float m = fmaxf(m0, m1);
    float s = s0 + s1;

    int ry0 = max(0, py - 1), ry1 = min(Hn - 1, py + 1);
    int rx0 = max(0, px - 1), rx1 = min(Wn - 1, px + 1);
    float rectc = 0.f;
    if (l < 9) {
        int q = (l * 11) >> 5;              // l/3 for l<=8
        int r = l - 3 * q;
        int ry = ry0 + q, rx = rx0 + r;
        if (ry <= ry1 && rx <= rx1) rectc = row[ry * Wn + rx];  // L1 hit
    }
    s -= rectc;
#pragma unroll
    for (int o = 8; o; o >>= 1) {
        s += __shfl_xor(s, o, 64);
        m = fmaxf(m, __shfl_xor(m, o, 64));
    }
    int n_pri = HWn - (ry1 - ry0 + 1) * (rx1 - rx0 + 1);
    float mean_pri = s / (float)n_pri;      // IEEE: feeds the keep-compare cliff

    // ---- Pass B: min over {c<=mean_pri} of (d2-1) unsigned; peak wraps ----
    int dxl = l - px;
    int dx2m1 = dxl * dxl - 1;
    unsigned A = (unsigned)(py * py + dx2m1);
    int Bs = 1 - 2 * py;
    unsigned dminb = 0xFFFFFFFFu;
#pragma unroll
    for (int j = 0; j < 18; ++j) {
        unsigned t = min(dminb, A);
        dminb = (c[j] <= mean_pri) ? t : dminb;
        A += (unsigned)Bs; Bs += 2;
    }
    int dyt = (l >> 1) - py;
    int dxt = 16 + (l & 1) - px;
    int dxt2m1 = dxt * dxt - 1;
#pragma unroll
    for (int s2 = 0; s2 < 3; ++s2) {
        int dy = dyt + 8 * s2;
        unsigned dd = (unsigned)(dy * dy + dxt2m1);
        if (s2 == 2 && !v20) dd = 0x7FFFFFFFu;
        unsigned t = min(dminb, dd);
        dminb = (c[18 + s2] <= mean_pri) ? t : dminb;
    }
#pragma unroll
    for (int o = 8; o; o >>= 1)
        dminb = min(dminb, (unsigned)__shfl_xor((int)dminb, o, 64));

    float width = (dminb > 577u) ? 100.f
                                 : __builtin_amdgcn_sqrtf((float)(dminb + 1u));
    unsigned rad2m1 = min(max(dminb, 1u), 19u);

    // ---- Pass C: survivors (d2-1 > rad2m1): sum, sumsq, in-disk count ----
    float sd0 = 0.f, sd1 = 0.f, ssd = 0.f;
    int cnt = 0;
    unsigned A2 = (unsigned)(py * py + dx2m1);
    int Bs2 = 1 - 2 * py;
#pragma unroll
    for (int j = 0; j < 18; ++j) {
        bool in = (A2 <= rad2m1);
        float cm = in ? 0.f : c[j];
        if (j & 1) sd1 += cm; else sd0 += cm;
        ssd = fmaf(cm, cm, ssd);
        cnt += in ? 1 : 0;
        A2 += (unsigned)Bs2; Bs2 += 2;
    }
#pragma unroll
    for (int s2 = 0; s2 < 3; ++s2) {
        int dy = dyt + 8 * s2;
        unsigned dd = (unsigned)(dy * dy + dxt2m1);
        if (s2 == 2 && !v20) dd = 0x7FFFFFFFu;
        bool in = (dd <= rad2m1);
        float cm = in ? 0.f : c[18 + s2];
        if (s2 & 1) sd1 += cm; else sd0 += cm;
        ssd = fmaf(cm, cm, ssd);
        cnt += in ? 1 : 0;
    }
    float sd = sd0 + sd1;
#pragma unroll
    for (int o = 8; o; o >>= 1) {
        sd  += __shfl_xor(sd, o, 64);
        ssd += __shfl_xor(ssd, o, 64);
        cnt += __shfl_xor(cnt, o, 64);
    }
    sd -= cpk;                               // peak is always in-disk
    ssd = fmaf(-cpk, cpk, ssd);
    float n = (float)(HWn - 1 - cnt);
    float mean_s = sd * __builtin_amdgcn_rcpf(n);
    float var_s = fmaf(-sd, mean_s, ssd) * __builtin_amdgcn_rcpf(n - 1.f);
    return (m - mean_s) * __builtin_amdgcn_rcpf(fmaf(var_s, width, 1e-16f));
}

// One 1024-thread block per batch row b: 16 waves x 4 tiles/iter x 6 iters
// cover the 324 channels; psrw values land in LDS; block-local reduction
// applies the mean-normalization. No cross-workgroup sync, no atomics.
// Register double-buffer (cA/cB) prefetches iteration i+1's tile during
// iteration i's compute to keep loads outstanding.
__global__ __launch_bounds__(1024) void psrw_fused(
    const float* __restrict__ cv, const int* __restrict__ peak,
    float* __restrict__ out)
{
    __shared__ float lds_psrw[CHn];
    __shared__ float wsum[16];
    __shared__ float inv_d;

    int b = blockIdx.x;
    int tid = threadIdx.x;
    int wid = tid >> 6;                 // 0..15
    int lane = tid & 63;
    int g = (tid >> 4) & 3;             // 16-lane group within wave
    int l = tid & 15;

    const float* cvb = cv + (size_t)b * CHn * HWn;
    const int*   pkb = peak + (size_t)b * CHn * 2;
    int lt0 = wid * 4 + g;              // iter-i tile = lt0 + 64*i

    float cA[21], cB[21];
    int2 pkA, pkB;
    float blk_sum = 0.f;

    load_tile(cvb, pkb, lt0, l, cA, pkA);
#pragma unroll
    for (int i = 0; i < 6; i += 2) {
        // prefetch i+1 into cB (iters 0..4 always valid; i=5 only wid==0)
        if (i + 1 < 6 && (i + 1) * 64 + wid * 4 < CHn)
            load_tile(cvb, pkb, lt0 + 64 * (i + 1), l, cB, pkB);
        if (i * 64 + wid * 4 < CHn) {
            int t = lt0 + 64 * i;
            float p = compute_psrw(cA, pkA, l, cvb + (size_t)t * HWn);
            if (l == 0) { lds_psrw[t] = p; blk_sum += p; }
        }
        if (i + 2 < 6 && (i + 2) * 64 + wid * 4 < CHn)
            load_tile(cvb, pkb, lt0 + 64 * (i + 2), l, cA, pkA);
        if (i + 1 < 6 && (i + 1) * 64 + wid * 4 < CHn) {
            int t = lt0 + 64 * (i + 1);
            float p = compute_psrw(cB, pkB, l, cvb + (size_t)t * HWn);
            if (l == 0) { lds_psrw[t] = p; blk_sum += p; }
        }
    }

    // ---- block-local normalization ----
    // blk_sum nonzero only at lanes 0,16,32,48: fold the 4 groups.
    blk_sum += __shfl_xor(blk_sum, 16, 64);
    blk_sum += __shfl_xor(blk_sum, 32, 64);
    if (lane == 0) wsum[wid] = blk_sum;
    __syncthreads();
    if (wid == 0) {
        float v = (lane < 16) ? wsum[lane] : 0.f;
#pragma unroll
        for (int o = 8; o; o >>= 1) v += __shfl_xor(v, o, 64);
        if (lane == 0) inv_d = 1.f / (v / 324.f + 1e-8f);
    }
    __syncthreads();
    float idv = inv_d;
    if (tid < CHn) out[(size_t)b * CHn + tid] = lds_psrw[tid] * idv;
}

extern "C" void kernel_launch(void* const* d_in, const int* in_sizes, int n_in,
                              void* d_out, int out_size, void* d_ws, size_t ws_size,
                              hipStream_t stream) {
    const float* cv  = (const float*)d_in[0];
    const int* peak  = (const int*)d_in[1];
    // d_in[2]/d_in[3] (mesh_y/mesh_x) are broadcast index grids — recomputed.
    float* out = (float*)d_out;

    int B = out_size / CHn;               // 256 batch rows, one block each
    psrw_fused<<<B, 1024, 0, stream>>>(cv, peak, out);
}

// Round 8
// 25.141 us; speedup vs baseline: 1.0938x; 1.0777x over previous
//
#include <hip/hip_runtime.h>
#include <math.h>

constexpr int Hn = 18, Wn = 18, HWn = 324;

// Four tiles per wave; 16-lane group g owns tile wave*4+g.
// Column layout: lane l owns column x=l via slots j=0..17 (element j*18+l),
// plus tails x in {16,17}: slot 18+s -> (y=8s+(l>>1), x=16+(l&1)); slot 20
// valid only for l<4.  dx^2 per lane is constant; d^2 walks a 2-add
// recurrence, RE-WALKED in pass C instead of stored (-21 VGPR), so the
// live set fits the 84-VGPR cap of __launch_bounds__(256,6) without
// spilling -> 6 waves/SIMD for latency hiding (round 4 was ~4).
__global__ __launch_bounds__(256, 6) void psrw_kernel(
    const float* __restrict__ cv, const int* __restrict__ peak,
    float* __restrict__ out, int BC)
{
    int gtid = blockIdx.x * 256 + threadIdx.x;
    int wave = gtid >> 6;
    int lane = threadIdx.x & 63;
    int g = lane >> 4;
    int l = lane & 15;
    int tile = wave * 4 + g;
    if (tile >= BC) return;

    const float* row = cv + (size_t)tile * HWn;
    int2 pk = ((const int2*)peak)[tile];
    int py = pk.x & 31, px = pk.y & 31;   // range-pin: enables mul24

    const float* colp = row + l;
    float c[21];
#pragma unroll
    for (int j = 0; j < 18; ++j) c[j] = colp[18 * j];   // imm-offset loads
    int lh = l >> 1, lb = l & 1;
    const float* tp = row + (lh * 18 + 16 + lb);
    c[18] = tp[0];
    c[19] = tp[144];
    bool v20 = (l < 4);
    c[20] = v20 ? tp[288] : 0.f;          // flat idx <= 323: always in-tile

    float cpk = row[py * Wn + px];        // peak value (uniform per group)

    // ---- Pass A: max + total sum; rect sum gathered by lanes 0..8 ----
    float m0 = -INFINITY, m1 = -INFINITY, s0 = 0.f, s1 = 0.f;
#pragma unroll
    for (int j = 0; j < 18; j += 2) { m0 = fmaxf(m0, c[j]); s0 += c[j]; }
#pragma unroll
    for (int j = 1; j < 18; j += 2) { m1 = fmaxf(m1, c[j]); s1 += c[j]; }
    m0 = fmaxf(m0, c[18]); s0 += c[18];
    m1 = fmaxf(m1, c[19]); s1 += c[19];
    m0 = fmaxf(m0, v20 ? c[20] : -INFINITY); s0 += c[20];
    float m = fmaxf(m0, m1);
    float s = s0 + s1;

    int ry0 = max(0, py - 1), ry1 = min(Hn - 1, py + 1);
    int rx0 = max(0, px - 1), rx1 = min(Wn - 1, px + 1);
    float rectc = 0.f;
    if (l < 9) {
        int q = (l * 11) >> 5;            // l/3 for l<=8
        int r = l - 3 * q;
        int ry = ry0 + q, rx = rx0 + r;
        if (ry <= ry1 && rx <= rx1) rectc = row[ry * Wn + rx];  // L1 hit
    }
    s -= rectc;                           // fold rect removal into reduction
#pragma unroll
    for (int o = 8; o; o >>= 1) {
        s += __shfl_xor(s, o, 64);
        m = fmaxf(m, __shfl_xor(m, o, 64));
    }
    int n_pri = HWn - (ry1 - ry0 + 1) * (rx1 - rx0 + 1);
    float mean_pri = s / (float)n_pri;    // IEEE: feeds the keep-compare cliff

    // ---- Pass B: dminb = min over {c<=mean_pri} of (d2-1), unsigned ----
    // ddm1 = dy^2 + (dx^2-1); peak (d2=0) wraps to 0xFFFFFFFF -> auto-excluded.
    int dxl = l - px;
    int dx2m1 = dxl * dxl - 1;
    unsigned A = (unsigned)(py * py + dx2m1);  // dy = -py at j=0
    int Bs = 1 - 2 * py;                       // A += 2*dy+1 per j
    unsigned dminb = 0xFFFFFFFFu;
#pragma unroll
    for (int j = 0; j < 18; ++j) {
        unsigned t = min(dminb, A);
        dminb = (c[j] <= mean_pri) ? t : dminb;
        A += (unsigned)Bs; Bs += 2;
    }
    int dyt = lh - py;
    int dxt = 16 + lb - px;
    int dxt2m1 = dxt * dxt - 1;
#pragma unroll
    for (int s2 = 0; s2 < 3; ++s2) {
        int dy = dyt + 8 * s2;
        unsigned dd = (unsigned)(dy * dy + dxt2m1);
        if (s2 == 2 && !v20) dd = 0x7FFFFFFFu;   // invalid slot: far, not in-disk
        unsigned t = min(dminb, dd);
        dminb = (c[18 + s2] <= mean_pri) ? t : dminb;
    }
#pragma unroll
    for (int o = 8; o; o >>= 1)
        dminb = min(dminb, (unsigned)__shfl_xor((int)dminb, o, 64));

    // width = sqrt(dmin) (sentinel 100); disk test d2 <= clip(dmin,2,20) exact
    float width = (dminb > 577u) ? 100.f
                                 : __builtin_amdgcn_sqrtf((float)(dminb + 1u));
    unsigned rad2m1 = min(max(dminb, 1u), 19u);

    // ---- Pass C: survivors (d2-1 > rad2m1): sum, sumsq, in-disk count ----
    float sd0 = 0.f, sd1 = 0.f, ssd = 0.f;
    int cnt = 0;
    unsigned A2 = (unsigned)(py * py + dx2m1);
    int Bs2 = 1 - 2 * py;
#pragma unroll
    for (int j = 0; j < 18; ++j) {
        bool in = (A2 <= rad2m1);         // peak: 0xFFFFFFFF -> "survivor" (fixed below)
        float cm = in ? 0.f : c[j];
        if (j & 1) sd1 += cm; else sd0 += cm;
        ssd = fmaf(cm, cm, ssd);
        cnt += in ? 1 : 0;
        A2 += (unsigned)Bs2; Bs2 += 2;
    }
#pragma unroll
    for (int s2 = 0; s2 < 3; ++s2) {
        int dy = dyt + 8 * s2;
        unsigned dd = (unsigned)(dy * dy + dxt2m1);
        if (s2 == 2 && !v20) dd = 0x7FFFFFFFu;
        bool in = (dd <= rad2m1);
        float cm = in ? 0.f : c[18 + s2];
        if (s2 & 1) sd1 += cm; else sd0 += cm;
        ssd = fmaf(cm, cm, ssd);
        cnt += in ? 1 : 0;
    }
    float sd = sd0 + sd1;
#pragma unroll
    for (int o = 8; o; o >>= 1) {
        sd  += __shfl_xor(sd, o, 64);
        ssd += __shfl_xor(ssd, o, 64);
        cnt += __shfl_xor(cnt, o, 64);
    }
    // peak correction: it is always in-disk (d2=0 <= rad2 since rad2>=2)
    sd -= cpk;
    ssd = fmaf(-cpk, cpk, ssd);
    float n = (float)(HWn - 1 - cnt);
    float mean_s = sd * __builtin_amdgcn_rcpf(n);
    float var_s = fmaf(-sd, mean_s, ssd) * __builtin_amdgcn_rcpf(n - 1.f);
    float psrw = (m - mean_s) * __builtin_amdgcn_rcpf(fmaf(var_s, width, 1e-16f));
    if (l == 0) out[tile] = psrw;
}

// Normalize each b-row of C=324 psrw values by (mean + 1e-8), in place.
__global__ __launch_bounds__(256) void norm_kernel(float* __restrict__ out, int B)
{
    int gtid = blockIdx.x * 256 + threadIdx.x;
    int wave = gtid >> 6;
    int lane = threadIdx.x & 63;
    if (wave >= B) return;
    float* row = out + (size_t)wave * HWn;
    float4 v0 = reinterpret_cast<float4*>(row)[lane];
    bool has2 = lane < 17;
    float4 v1 = make_float4(0.f, 0.f, 0.f, 0.f);
    if (has2) v1 = reinterpret_cast<float4*>(row)[64 + lane];
    float s = (v0.x + v0.y) + (v0.z + v0.w) + ((v1.x + v1.y) + (v1.z + v1.w));
#pragma unroll
    for (int o = 32; o; o >>= 1) s += __shfl_xor(s, o, 64);
    float denom = s / 324.0f + 1e-8f;
    v0.x /= denom; v0.y /= denom; v0.z /= denom; v0.w /= denom;
    reinterpret_cast<float4*>(row)[lane] = v0;
    if (has2) {
        v1.x /= denom; v1.y /= denom; v1.z /= denom; v1.w /= denom;
        reinterpret_cast<float4*>(row)[64 + lane] = v1;
    }
}

extern "C" void kernel_launch(void* const* d_in, const int* in_sizes, int n_in,
                              void* d_out, int out_size, void* d_ws, size_t ws_size,
                              hipStream_t stream) {
    const float* cv  = (const float*)d_in[0];
    const int* peak  = (const int*)d_in[1];
    // d_in[2]/d_in[3] (mesh_y/mesh_x) are broadcast index grids — recomputed.
    float* out = (float*)d_out;

    int BC = in_sizes[1] / 2;               // 82944 tiles
    int waves = (BC + 3) / 4;               // 4 tiles per wave
    int blocks1 = (waves + 3) / 4;          // 4 waves per 256-thread block
    psrw_kernel<<<blocks1, 256, 0, stream>>>(cv, peak, out, BC);

    int B = out_size / HWn;
    int blocks2 = (B + 3) / 4;
    norm_kernel<<<blocks2, 256, 0, stream>>>(out, B);
}